// Round 14
// baseline (939.451 us; speedup 1.0000x reference)
//
#include <hip/hip_runtime.h>
#include <stdint.h>

#define NN 10000      // nodes
#define NE 160000     // edges (paired: e and e^1 are fwd/rev)
#define HID 300
#define PH 304        // padded row stride (bf16 rows 608B; 16B-aligned)
#define NF 133
#define EF 14
#define NG 64

#define BR 32         // rows per MODE0/2 block
#define CBR 64        // rows per conv block
#define NT 19         // n-tiles of 16 (304 padded cols)
#define WGRAN (NT*64) // 1216 16B-granules of W per k-step
#define CSTRIDE 304   // LDS C-tile column stride (ushorts)

typedef __bf16 bf16x8 __attribute__((ext_vector_type(8)));
typedef float f32x4 __attribute__((ext_vector_type(4)));

union GR { bf16x8 v; unsigned short s[8]; uint4 u; };

__device__ __forceinline__ float bf2f(unsigned short u) {
  union { unsigned int i; float f; } x; x.i = ((unsigned int)u) << 16; return x.f;
}
__device__ __forceinline__ unsigned short f2bf(float f) {
  union { float f; unsigned int i; } x; x.f = f;
  unsigned int r = x.i + 0x7fffu + ((x.i >> 16) & 1u);
  return (unsigned short)(r >> 16);
}

// ---------------- small utilities ----------------
__global__ void zero_kernel(int* __restrict__ p, int n) {
  int i = blockIdx.x * 256 + threadIdx.x;
  if (i < n) p[i] = 0;
}

// ---------------- CSR build over col ----------------
__global__ void hist_kernel(const int* __restrict__ col, int* __restrict__ cnt) {
  int e = blockIdx.x * 256 + threadIdx.x;
  if (e < NE) atomicAdd(&cnt[col[e]], 1);
}

__global__ void scan_kernel(const int* __restrict__ cnt, int* __restrict__ indptr) {
  __shared__ int part[1024];
  int t = threadIdx.x;
  int base = t * 10;
  int loc[10];
  int s = 0;
  #pragma unroll
  for (int i = 0; i < 10; ++i) {
    int n = base + i;
    int v = (n < NN) ? cnt[n] : 0;
    loc[i] = s; s += v;
  }
  part[t] = s;
  __syncthreads();
  for (int off = 1; off < 1024; off <<= 1) {
    int v = part[t];
    int u = (t >= off) ? part[t - off] : 0;
    __syncthreads();
    part[t] = v + u;
    __syncthreads();
  }
  int pre = (t == 0) ? 0 : part[t - 1];
  #pragma unroll
  for (int i = 0; i < 10; ++i) {
    int n = base + i;
    if (n <= NN) indptr[n] = pre + loc[i];
  }
}

__global__ void scatter_kernel(const int* __restrict__ col, const int* __restrict__ indptr,
                               int* __restrict__ cnt, int* __restrict__ eids) {
  int e = blockIdx.x * 256 + threadIdx.x;
  if (e < NE) {
    int v = col[e];
    int p = atomicSub(&cnt[v], 1) - 1;
    eids[indptr[v] + p] = e;
  }
}

// ---- segment_sum(h[bf16,PH], col) -> a[bf16,PH]: 16B granules, 6 slots -----
__global__ __launch_bounds__(256)
void segsum_kernel(const unsigned short* __restrict__ h,
                   const int* __restrict__ indptr, const int* __restrict__ eids,
                   unsigned short* __restrict__ a) {
  __shared__ float part[6][PH];
  const int v = blockIdx.x;
  const int t = threadIdx.x;
  const int beg = indptr[v], end = indptr[v + 1];
  if (t < 228) {
    const int g = t % 38;          // 16B granule (8 cols)
    const int s = t / 38;          // row slot 0..5
    const int c8 = g << 3;
    float A[8], B[8];
    #pragma unroll
    for (int q = 0; q < 8; ++q) { A[q] = 0.f; B[q] = 0.f; }
    int p = beg + s;
    for (; p + 12 <= end; p += 12) {
      const int e0 = eids[p], e1 = eids[p + 6];
      GR h0v, h1v;
      h0v.u = *(const uint4*)(h + (size_t)e0 * PH + c8);
      h1v.u = *(const uint4*)(h + (size_t)e1 * PH + c8);
      #pragma unroll
      for (int q = 0; q < 8; ++q) { A[q] += bf2f(h0v.s[q]); B[q] += bf2f(h1v.s[q]); }
    }
    if (p < end) {                 // tail step 1
      GR h0v; h0v.u = *(const uint4*)(h + (size_t)eids[p] * PH + c8);
      #pragma unroll
      for (int q = 0; q < 8; ++q) A[q] += bf2f(h0v.s[q]);
      p += 6;
    }
    if (p < end) {                 // tail step 2
      GR h1v; h1v.u = *(const uint4*)(h + (size_t)eids[p] * PH + c8);
      #pragma unroll
      for (int q = 0; q < 8; ++q) B[q] += bf2f(h1v.s[q]);
    }
    #pragma unroll
    for (int q = 0; q < 8; ++q) part[s][c8 + q] = A[q] + B[q];
  }
  __syncthreads();
  if (t < 38) {
    GR o;
    #pragma unroll
    for (int q = 0; q < 8; ++q) {
      float r = 0.f;
      #pragma unroll
      for (int s = 0; s < 6; ++s) r += part[s][(t << 3) + q];
      o.s[q] = f2bf(r);
    }
    *(uint4*)(a + (size_t)v * PH + (t << 3)) = o.u;
  }
}

// ---------------- weight pre-transpose (pos + optional neg copy) ------------
__global__ void wtrans_kernel(const float* __restrict__ W, int K,
                              unsigned short* __restrict__ dst,
                              unsigned short* __restrict__ dstn) {
  const int b = blockIdx.x;          // kt*NT + nt
  const int l = threadIdx.x;         // 0..63
  const int kt = b / NT, nt = b - kt * NT;
  const int k0 = kt * 32 + ((l >> 4) << 3);
  const int n  = (nt << 4) + (l & 15);
  GR g, gn;
  #pragma unroll
  for (int i = 0; i < 8; ++i) {
    const int k = k0 + i;
    float f = (k < K && n < HID) ? W[(size_t)k * HID + n] : 0.f;
    g.s[i] = f2bf(f);
    gn.s[i] = f2bf(-f);
  }
  *(uint4*)(dst + ((size_t)(b * 64 + l) << 3)) = g.u;
  if (dstn) *(uint4*)(dstn + ((size_t)(b * 64 + l) << 3)) = gn.u;
}

// ---------------- conv: split-GEMM h = relu(a@W + h^1@(-W) + b + h0) --------
// 64 rows x 304 cols, 8 waves (ntg = wave&3 -> 5 n-tiles, etg = wave>>2 ->
// 32-row half). Staging = RAW bf16 copies (a gather + linear h^1), zero VALU.
// Subtract happens on the matrix pipe via the negated W copy.
__global__ __launch_bounds__(512, 4)
void conv_kernel(const int* __restrict__ rowidx,
                 const unsigned short* __restrict__ abf,   // a bf16 [PH]
                 const unsigned short* hcur,               // may alias outA
                 const unsigned short* __restrict__ h0,
                 const unsigned short* __restrict__ wpos,
                 const unsigned short* __restrict__ wneg,
                 const float* __restrict__ bias,
                 unsigned short* outA)
{
  __shared__ unsigned short S_a[38 * CBR * 8];   // 38912 B; reused as C-tile
  __shared__ unsigned short S_h[38 * CBR * 8];   // 38912 B
  __shared__ int rowv[CBR];

  const int t = threadIdx.x;
  const int l = t & 63;
  const int wave = t >> 6;
  const int ntg = wave & 3;
  const int etg = wave >> 2;         // 0..1
  const int lr = l & 15;
  const int lg = l >> 4;
  const int r0 = blockIdx.x * CBR;
  const int nt0 = ntg * 5;
  const int ntc = (ntg == 3) ? 4 : 5;

  if (t < CBR) rowv[t] = rowidx[r0 + t];
  __syncthreads();

  // ---- stage both operands: raw uint4 copies, all loads issued up front ----
  {
    const int row = t & 63;          // fixed per thread
    const int kg0 = t >> 6;          // 0..7
    const unsigned short* ap = abf + (size_t)rowv[row] * PH;
    const unsigned short* hp = hcur + (size_t)((r0 + row) ^ 1) * PH;
    uint4 va[5], vh[5];
    #pragma unroll
    for (int j = 0; j < 5; ++j) {
      const int kg = kg0 + 8 * j;
      if (kg < 38) {
        va[j] = *(const uint4*)(ap + (kg << 3));
        vh[j] = *(const uint4*)(hp + (kg << 3));
      }
    }
    #pragma unroll
    for (int j = 0; j < 5; ++j) {
      const int kg = kg0 + 8 * j;
      if (kg < 38) {
        *(uint4*)(S_a + (size_t)((kg << 6) + row) * 8) = va[j];
        *(uint4*)(S_h + (size_t)((kg << 6) + row) * 8) = vh[j];
      }
    }
  }
  __syncthreads();

  f32x4 acc[5][2];
  #pragma unroll
  for (int ni = 0; ni < 5; ++ni)
    #pragma unroll
    for (int i = 0; i < 2; ++i) acc[ni][i] = (f32x4)0.f;

  // ---- k-loop: a@(+W) and h^1@(-W) into the same accumulator ----
  #pragma unroll
  for (int kt = 0; kt < 10; ++kt) {
    int kg = kt * 4 + lg;
    if (kt * 4 + 3 >= 38) kg = (kg < 38) ? kg : 0;   // W is zero there anyway
    bf16x8 ea[2], eh[2];
    #pragma unroll
    for (int i = 0; i < 2; ++i) {
      const int row16 = etg * 32 + i * 16 + lr;
      ea[i] = *(const bf16x8*)(S_a + (size_t)((kg << 6) + row16) * 8);
      eh[i] = *(const bf16x8*)(S_h + (size_t)((kg << 6) + row16) * 8);
    }
    const unsigned short* wkp = wpos + (((size_t)kt * WGRAN + nt0 * 64 + l) << 3);
    const unsigned short* wkn = wneg + (((size_t)kt * WGRAN + nt0 * 64 + l) << 3);
    #pragma unroll
    for (int ni = 0; ni < 5; ++ni) {
      if (ni < ntc) {
        const bf16x8 wfp = *(const bf16x8*)(wkp + ((size_t)ni << 9));
        const bf16x8 wfn = *(const bf16x8*)(wkn + ((size_t)ni << 9));
        #pragma unroll
        for (int i = 0; i < 2; ++i) {
          acc[ni][i] = __builtin_amdgcn_mfma_f32_16x16x32_bf16(wfp, ea[i], acc[ni][i], 0, 0, 0);
          acc[ni][i] = __builtin_amdgcn_mfma_f32_16x16x32_bf16(wfn, eh[i], acc[ni][i], 0, 0, 0);
        }
      }
    }
  }

  // ---- stage C tile (acc + bias, pre-relu) into LDS (reuses S_a) ----
  __syncthreads();
  #pragma unroll
  for (int ni = 0; ni < 5; ++ni) {
    if (ni >= ntc) continue;
    const int n = ((nt0 + ni) << 4) + (lg << 2);
    float4 bv = make_float4(0.f, 0.f, 0.f, 0.f);
    if (n < HID) bv = *(const float4*)(bias + n);
    #pragma unroll
    for (int i = 0; i < 2; ++i) {
      const int row = etg * 32 + i * 16 + lr;
      ushort4 o;
      o.x = f2bf(acc[ni][i][0] + bv.x);
      o.y = f2bf(acc[ni][i][1] + bv.y);
      o.z = f2bf(acc[ni][i][2] + bv.z);
      o.w = f2bf(acc[ni][i][3] + bv.w);
      *(ushort4*)(S_a + row * CSTRIDE + n) = o;
    }
  }
  __syncthreads();

  // ---- linear write-out, 16B/lane: 64 rows x 38 uint4 granules ----
  {
    const size_t base = (size_t)r0 * PH;
    constexpr int WPIECE = CBR * 38;               // 2432
    GR hz[5];
    int srow[5], sidx[5]; bool ok[5];
    #pragma unroll
    for (int j = 0; j < 5; ++j) {
      const int s = t + (j << 9);
      ok[j] = (s < WPIECE);
      if (ok[j]) {
        srow[j] = s / 38; sidx[j] = s - srow[j] * 38;
        hz[j].u = *(const uint4*)(h0 + base + (size_t)srow[j] * PH + (sidx[j] << 3));
      }
    }
    #pragma unroll
    for (int j = 0; j < 5; ++j) {
      if (!ok[j]) continue;
      GR c; c.u = *(const uint4*)(S_a + srow[j] * CSTRIDE + (sidx[j] << 3));
      GR o;
      #pragma unroll
      for (int q = 0; q < 8; ++q)
        o.s[q] = f2bf(fmaxf(bf2f(c.s[q]) + bf2f(hz[j].s[q]), 0.f));
      *(uint4*)(outA + base + (size_t)srow[j] * PH + (sidx[j] << 3)) = o.u;
    }
  }
}

// ---------------- MFMA GEMM for MODE 0 (edge-init) / MODE 2 (node MLP) ------
template<int MODE, int KTILES>
__global__ __launch_bounds__(256, 5)
void gemm_kernel(const float* __restrict__ xin,
                 const int* __restrict__ rowidx,
                 const float* __restrict__ eaux,       // MODE0: edge_attr (f32)
                 const unsigned short* __restrict__ saux, // MODE2: s (bf16, PH)
                 const unsigned short* __restrict__ wbt,
                 const float* __restrict__ bias,
                 unsigned short* outA,
                 float* __restrict__ outF)
{
  constexpr int KEFF = (MODE == 0) ? (NF + EF) : (NF + HID);
  constexpr int NKG_A = (KEFF + 7) / 8;
  constexpr int STAGE_USH = NKG_A * BR * 8;
  constexpr int LDS_USH = (MODE == 2) ? STAGE_USH
                        : ((STAGE_USH > BR * CSTRIDE) ? STAGE_USH : BR * CSTRIDE);
  __shared__ unsigned short S_lds[LDS_USH];
  __shared__ int rowv[BR];

  const int t = threadIdx.x;
  const int l = t & 63;
  const int wave = t >> 6;
  const int lr = l & 15;
  const int lg = l >> 4;
  const int r0 = blockIdx.x * BR;
  const int nt0 = wave * 5;
  const int ntc = (wave == 3) ? 4 : 5;

  if (MODE == 0 && t < BR) rowv[t] = rowidx[r0 + t];
  __syncthreads();

  {
    constexpr int PIECES = STAGE_USH / 4;
    constexpr int SITER = (PIECES + 255) / 256;
    const int a_row = (t >> 1) & 31;
    const int a_c   = t >> 6;
    const int a_h4  = (t & 1) << 2;
    const int rv    = (MODE == 2) ? (r0 + a_row) : rowv[a_row];
    const float* xp = xin + (size_t)rv * NF;
    const float* ap = (MODE == 0) ? eaux + (size_t)(r0 + a_row) * EF - NF : nullptr;
    const unsigned short* sp = (MODE == 2) ? saux + (size_t)rv * PH : nullptr;
    const bool node_ok = (MODE != 2) || (rv < NN);
    #pragma unroll
    for (int b0 = 0; b0 < SITER; b0 += 4) {
      unsigned short uv[4][4];
      #pragma unroll
      for (int j = 0; j < 4; ++j) {
        const int it = b0 + j;
        if (it >= SITER) continue;
        const bool ok = (t + (it << 8)) < PIECES;
        const int k = ((a_c + 4 * it) << 3) + a_h4;
        #pragma unroll
        for (int q = 0; q < 4; ++q) {
          const int kk = k + q;
          unsigned short u = 0;
          if (ok && node_ok) {
            if (kk < NF) u = f2bf(xp[kk]);
            else if (kk < KEFF) u = (MODE == 0) ? f2bf(ap[kk]) : sp[kk - NF];
          }
          uv[j][q] = u;
        }
      }
      #pragma unroll
      for (int j = 0; j < 4; ++j) {
        const int it = b0 + j;
        if (it >= SITER) continue;
        if ((t + (it << 8)) >= PIECES) continue;
        ushort4 o;
        o.x = uv[j][0]; o.y = uv[j][1]; o.z = uv[j][2]; o.w = uv[j][3];
        *(ushort4*)(S_lds + (size_t)(t + (it << 8)) * 4) = o;
      }
    }
  }
  __syncthreads();

  f32x4 acc[5][2];
  #pragma unroll
  for (int ni = 0; ni < 5; ++ni)
    #pragma unroll
    for (int i = 0; i < 2; ++i) acc[ni][i] = (f32x4)0.f;

  constexpr int NKG = (KEFF + 7) / 8;
  #pragma unroll
  for (int kt = 0; kt < KTILES; ++kt) {
    int kg = kt * 4 + lg;
    if (kt * 4 + 3 >= NKG) kg = (kg < NKG) ? kg : 0;
    bf16x8 ef[2];
    #pragma unroll
    for (int i = 0; i < 2; ++i)
      ef[i] = *(const bf16x8*)(S_lds + (size_t)((kg * BR + i * 16 + lr)) * 8);
    const unsigned short* wk = wbt + (((size_t)kt * WGRAN + nt0 * 64 + l) << 3);
    #pragma unroll
    for (int ni = 0; ni < 5; ++ni) {
      if (ni < ntc) {
        const bf16x8 wf = *(const bf16x8*)(wk + ((size_t)ni << 9));
        #pragma unroll
        for (int i = 0; i < 2; ++i)
          acc[ni][i] = __builtin_amdgcn_mfma_f32_16x16x32_bf16(wf, ef[i], acc[ni][i], 0, 0, 0);
      }
    }
  }

  if (MODE == 2) {
    #pragma unroll
    for (int ni = 0; ni < 5; ++ni) {
      if (ni >= ntc) continue;
      const int n = ((nt0 + ni) << 4) + (lg << 2);
      if (n >= HID) continue;
      const float4 bv = *(const float4*)(bias + n);
      #pragma unroll
      for (int i = 0; i < 2; ++i) {
        const int node = r0 + (i << 4) + lr;
        if (node >= NN) continue;
        float v0 = fmaxf(acc[ni][i][0] + bv.x, 0.f);
        float v1 = fmaxf(acc[ni][i][1] + bv.y, 0.f);
        float v2 = fmaxf(acc[ni][i][2] + bv.z, 0.f);
        float v3 = fmaxf(acc[ni][i][3] + bv.w, 0.f);
        *(float4*)(outF + (size_t)node * HID + n) = make_float4(v0, v1, v2, v3);
      }
    }
    return;
  }

  // ---- MODE 0 epilogue: bias+relu, C-tile, 16B/lane write ----
  __syncthreads();
  #pragma unroll
  for (int ni = 0; ni < 5; ++ni) {
    if (ni >= ntc) continue;
    const int n = ((nt0 + ni) << 4) + (lg << 2);
    float4 bv = make_float4(0.f, 0.f, 0.f, 0.f);
    if (n < HID) bv = *(const float4*)(bias + n);
    #pragma unroll
    for (int i = 0; i < 2; ++i) {
      const int row = (i << 4) + lr;
      ushort4 o;
      o.x = f2bf(fmaxf(acc[ni][i][0] + bv.x, 0.f));
      o.y = f2bf(fmaxf(acc[ni][i][1] + bv.y, 0.f));
      o.z = f2bf(fmaxf(acc[ni][i][2] + bv.z, 0.f));
      o.w = f2bf(fmaxf(acc[ni][i][3] + bv.w, 0.f));
      *(ushort4*)(S_lds + row * CSTRIDE + n) = o;
    }
  }
  __syncthreads();
  {
    const size_t base = (size_t)r0 * PH;
    constexpr int WPIECE = BR * 38;               // 1216
    #pragma unroll
    for (int j = 0; j < 5; ++j) {
      const int s = t + (j << 8);
      if (s >= WPIECE) continue;
      const int row = s / 38;
      const int idx = s - row * 38;
      const uint4 c = *(const uint4*)(S_lds + row * CSTRIDE + (idx << 3));
      *(uint4*)(outA + base + (size_t)row * PH + (idx << 3)) = c;
    }
  }
}

// ---------------- output init + fused dot/pool ----------------
__global__ void init_out_kernel(float* __restrict__ out, const float* __restrict__ b_ffn) {
  int t = threadIdx.x;
  if (t < NG) out[t] = b_ffn[0];
}

__global__ void dotpool_kernel(const float* __restrict__ hn, const float* __restrict__ wffn,
                               const int* __restrict__ batch, float* __restrict__ out) {
  const int wave = threadIdx.x >> 6, lane = threadIdx.x & 63;
  const int v = blockIdx.x * 4 + wave;
  if (v >= NN) return;
  float s = 0.f;
  for (int j = lane; j < HID; j += 64) s += hn[(size_t)v * HID + j] * wffn[j];
  #pragma unroll
  for (int off = 32; off > 0; off >>= 1) s += __shfl_down(s, off, 64);
  if (lane == 0) atomicAdd(&out[batch[v]], s);
}

// ---------------- launch ----------------
extern "C" void kernel_launch(void* const* d_in, const int* in_sizes, int n_in,
                              void* d_out, int out_size, void* d_ws, size_t ws_size,
                              hipStream_t stream) {
  const float* x     = (const float*)d_in[0];
  const int*   eidx  = (const int*)d_in[1];
  const float* eattr = (const float*)d_in[2];
  const int*   batch = (const int*)d_in[3];
  const float* W_ei  = (const float*)d_in[4];
  const float* b_ei  = (const float*)d_in[5];
  const float* Ws    = (const float*)d_in[6];
  const float* bs    = (const float*)d_in[7];
  const float* W_en  = (const float*)d_in[8];
  const float* b_en  = (const float*)d_in[9];
  const float* W_ffn = (const float*)d_in[10];
  const float* b_ffn = (const float*)d_in[11];
  float* out = (float*)d_out;

  const int* row  = eidx;
  const int* colv = eidx + NE;

  // workspace layout (~215 MB), PH=304-stride rows 16B-aligned
  char* ws = (char*)d_ws;
  unsigned short* h0  = (unsigned short*)(ws + 0);              //  97,280,000 B
  unsigned short* h   = (unsigned short*)(ws + 97280000ull);    //  97,280,000 B
  unsigned short* abf = (unsigned short*)(ws + 194560000ull);   //   6,080,000 B (bf16)
  float* hn           = (float*)(ws + 200640000ull);            //  12,000,000 B (stride 300)
  int* indptr         = (int*)(ws + 212640000ull);              //      40,004 B
  int* cnt            = (int*)(ws + 212680192ull);              //      40,000 B
  int* eids           = (int*)(ws + 212720384ull);              //     640,000 B
  unsigned short* wbt0  = (unsigned short*)(ws + 213360384ull); //      97,280 B
  unsigned short* wbtC  = (unsigned short*)(ws + 213457664ull); //     583,680 B (3 layers)
  unsigned short* wbtCn = (unsigned short*)(ws + 214041344ull); //     583,680 B (negated)
  unsigned short* wbtN  = (unsigned short*)(ws + 214625024ull); //     272,384 B

  // CSR over col (scatter restores cnt to 0)
  zero_kernel<<<(NN + 255) / 256, 256, 0, stream>>>(cnt, NN);
  hist_kernel<<<NE / 256, 256, 0, stream>>>(colv, cnt);
  scan_kernel<<<1, 1024, 0, stream>>>(cnt, indptr);
  scatter_kernel<<<NE / 256, 256, 0, stream>>>(colv, indptr, cnt, eids);

  // weight pre-transposes
  wtrans_kernel<<<5 * NT, 64, 0, stream>>>(W_ei, NF + EF, wbt0, nullptr);
  for (int lyr = 0; lyr < 3; ++lyr)
    wtrans_kernel<<<10 * NT, 64, 0, stream>>>(Ws + (size_t)lyr * HID * HID, HID,
                                              wbtC + (size_t)lyr * 10 * WGRAN * 8,
                                              wbtCn + (size_t)lyr * 10 * WGRAN * 8);
  wtrans_kernel<<<14 * NT, 64, 0, stream>>>(W_en, NF + HID, wbtN, nullptr);

  // h0 = relu([x[row]|ea] @ W_ei + b_ei)
  gemm_kernel<0, 5><<<NE / BR, 256, 0, stream>>>(
      x, row, eattr, nullptr, wbt0, b_ei, h0, nullptr);

  // layer 0: a = segsum(h0); h = relu(a@W0 + h0^1@(-W0) + b0 + h0)
  segsum_kernel<<<NN, 256, 0, stream>>>(h0, indptr, eids, abf);
  conv_kernel<<<NE / CBR, 512, 0, stream>>>(row, abf, h0, h0, wbtC, wbtCn, bs, h);

  // layers 1,2: in-place on h
  for (int lyr = 1; lyr < 3; ++lyr) {
    segsum_kernel<<<NN, 256, 0, stream>>>(h, indptr, eids, abf);
    conv_kernel<<<NE / CBR, 512, 0, stream>>>(
        row, abf, h, h0,
        wbtC + (size_t)lyr * 10 * WGRAN * 8,
        wbtCn + (size_t)lyr * 10 * WGRAN * 8,
        bs + (size_t)lyr * HID, h);
  }

  // s = segsum(h, col); hn = relu([x|s] @ W_en + b_en)
  segsum_kernel<<<NN, 256, 0, stream>>>(h, indptr, eids, abf);
  gemm_kernel<2, 14><<<(NN + BR - 1) / BR, 256, 0, stream>>>(
      x, nullptr, nullptr, abf, wbtN, b_en, nullptr, hn);

  // out[g] = b_ffn + sum_{batch[v]=g} hn[v] . W_ffn
  init_out_kernel<<<1, 64, 0, stream>>>(out, b_ffn);
  dotpool_kernel<<<NN / 4, 256, 0, stream>>>(hn, W_ffn, batch, out);
}

// Round 15
// 573.228 us; speedup vs baseline: 1.6389x; 1.6389x over previous
//
#include <hip/hip_runtime.h>
#include <stdint.h>

#define NN 10000      // nodes
#define NE 160000     // edges (paired: e and e^1 are fwd/rev)
#define HID 300
#define PH 304        // padded row stride (bf16 rows 608B; 16B-aligned)
#define NF 133
#define EF 14
#define NG 64

#define BR 32         // rows per GEMM/conv block (pairs stay inside block)
#define NT 19         // n-tiles of 16 (304 padded cols)
#define WGRAN (NT*64) // 1216 16B-granules of W per k-step
#define CSTRIDE 312   // LDS C-tile column stride; 156 dwords, gcd-safe (R13 had
                      // 304 -> 8-way bank conflict, 2.28M SQ_LDS_BANK_CONFLICT)

typedef __bf16 bf16x8 __attribute__((ext_vector_type(8)));
typedef float f32x4 __attribute__((ext_vector_type(4)));

union GR { bf16x8 v; unsigned short s[8]; uint4 u; };

__device__ __forceinline__ float bf2f(unsigned short u) {
  union { unsigned int i; float f; } x; x.i = ((unsigned int)u) << 16; return x.f;
}
__device__ __forceinline__ unsigned short f2bf(float f) {
  __bf16 b = (__bf16)f;                      // HW cvt (RNE) — cheaper than manual
  return __builtin_bit_cast(unsigned short, b);
}

// ---------------- small utilities ----------------
__global__ void zero_kernel(int* __restrict__ p, int n) {
  int i = blockIdx.x * 256 + threadIdx.x;
  if (i < n) p[i] = 0;
}

// ---------------- CSR build over col ----------------
__global__ void hist_kernel(const int* __restrict__ col, int* __restrict__ cnt) {
  int e = blockIdx.x * 256 + threadIdx.x;
  if (e < NE) atomicAdd(&cnt[col[e]], 1);
}

__global__ void scan_kernel(const int* __restrict__ cnt, int* __restrict__ indptr) {
  __shared__ int part[1024];
  int t = threadIdx.x;
  int base = t * 10;
  int loc[10];
  int s = 0;
  #pragma unroll
  for (int i = 0; i < 10; ++i) {
    int n = base + i;
    int v = (n < NN) ? cnt[n] : 0;
    loc[i] = s; s += v;
  }
  part[t] = s;
  __syncthreads();
  for (int off = 1; off < 1024; off <<= 1) {
    int v = part[t];
    int u = (t >= off) ? part[t - off] : 0;
    __syncthreads();
    part[t] = v + u;
    __syncthreads();
  }
  int pre = (t == 0) ? 0 : part[t - 1];
  #pragma unroll
  for (int i = 0; i < 10; ++i) {
    int n = base + i;
    if (n <= NN) indptr[n] = pre + loc[i];
  }
}

__global__ void scatter_kernel(const int* __restrict__ col, const int* __restrict__ indptr,
                               int* __restrict__ cnt, int* __restrict__ eids) {
  int e = blockIdx.x * 256 + threadIdx.x;
  if (e < NE) {
    int v = col[e];
    int p = atomicSub(&cnt[v], 1) - 1;
    eids[indptr[v] + p] = e;
  }
}

// ---- segment_sum(h[bf16,PH], col) -> a[bf16,PH]: 16B granules, 6 slots -----
#define PSTR 308   // part stride (f32): 308%32=20, gcd 4 -> spread banks
__global__ __launch_bounds__(256)
void segsum_kernel(const unsigned short* __restrict__ h,
                   const int* __restrict__ indptr, const int* __restrict__ eids,
                   unsigned short* __restrict__ a) {
  __shared__ float part[6][PSTR];
  const int v = blockIdx.x;
  const int t = threadIdx.x;
  const int beg = indptr[v], end = indptr[v + 1];
  if (t < 228) {
    const int g = t % 38;          // 16B granule (8 cols)
    const int s = t / 38;          // row slot 0..5
    const int c8 = g << 3;
    float A[8], B[8];
    #pragma unroll
    for (int q = 0; q < 8; ++q) { A[q] = 0.f; B[q] = 0.f; }
    int p = beg + s;
    for (; p + 12 <= end; p += 12) {
      const int e0 = eids[p], e1 = eids[p + 6];
      GR h0v, h1v;
      h0v.u = *(const uint4*)(h + (size_t)e0 * PH + c8);
      h1v.u = *(const uint4*)(h + (size_t)e1 * PH + c8);
      #pragma unroll
      for (int q = 0; q < 8; ++q) { A[q] += bf2f(h0v.s[q]); B[q] += bf2f(h1v.s[q]); }
    }
    if (p < end) {                 // tail step 1
      GR h0v; h0v.u = *(const uint4*)(h + (size_t)eids[p] * PH + c8);
      #pragma unroll
      for (int q = 0; q < 8; ++q) A[q] += bf2f(h0v.s[q]);
      p += 6;
    }
    if (p < end) {                 // tail step 2
      GR h1v; h1v.u = *(const uint4*)(h + (size_t)eids[p] * PH + c8);
      #pragma unroll
      for (int q = 0; q < 8; ++q) B[q] += bf2f(h1v.s[q]);
    }
    #pragma unroll
    for (int q = 0; q < 8; ++q) part[s][c8 + q] = A[q] + B[q];
  }
  __syncthreads();
  if (t < 38) {
    GR o;
    #pragma unroll
    for (int q = 0; q < 8; ++q) {
      float r = 0.f;
      #pragma unroll
      for (int s = 0; s < 6; ++s) r += part[s][(t << 3) + q];
      o.s[q] = f2bf(r);
    }
    *(uint4*)(a + (size_t)v * PH + (t << 3)) = o.u;
  }
}

// ---------------- weight pre-transpose into MFMA fragment order -------------
__global__ void wtrans_kernel(const float* __restrict__ W, int K,
                              unsigned short* __restrict__ dst) {
  const int b = blockIdx.x;          // kt*NT + nt
  const int l = threadIdx.x;         // 0..63
  const int kt = b / NT, nt = b - kt * NT;
  const int k0 = kt * 32 + ((l >> 4) << 3);
  const int n  = (nt << 4) + (l & 15);
  GR g;
  #pragma unroll
  for (int i = 0; i < 8; ++i) {
    const int k = k0 + i;
    float f = (k < K && n < HID) ? W[(size_t)k * HID + n] : 0.f;
    g.s[i] = f2bf(f);
  }
  *(uint4*)(dst + ((size_t)(b * 64 + l) << 3)) = g.u;
}

// ---------------- conv: h_out[e] = relu((a[row]-h^1)@W + b + h0[e]) ---------
// R13 structure: 32 rows x 304 cols, 4 waves x 5 n-tiles, 5 blocks/CU.
// a in bf16 (16B granules), staging batch-3 (regs stay under the /5 cap).
__global__ __launch_bounds__(256, 5)
void conv_kernel(const int* __restrict__ rowidx,
                 const unsigned short* __restrict__ abf,   // a bf16 [PH]
                 const unsigned short* hcur,               // may alias outA
                 const unsigned short* __restrict__ h0,
                 const unsigned short* __restrict__ wbt,
                 const float* __restrict__ bias,
                 unsigned short* outA)
{
  constexpr int LDS_USH = BR * CSTRIDE;          // 9984 ush = 19968B (> 38*32*8)
  __shared__ unsigned short S_lds[LDS_USH];      // A-stage, then C-tile
  __shared__ int rowv[BR];

  const int t = threadIdx.x;
  const int l = t & 63;
  const int wave = t >> 6;
  const int lr = l & 15;
  const int lg = l >> 4;
  const int r0 = blockIdx.x * BR;
  const int nt0 = wave * 5;
  const int ntc = (wave == 3) ? 4 : 5;

  if (t < BR) rowv[t] = rowidx[r0 + t];
  __syncthreads();

  // ---- stage (a[row]-h^1) once, 16B granules, batch-3 ----
  // row = t&31 (fixed), kg = (t>>5) + 8j, j<5
  {
    const int a_row = t & 31;
    const int kg0   = t >> 5;        // 0..7
    const unsigned short* ap = abf + (size_t)rowv[a_row] * PH;
    const unsigned short* hp = hcur + (size_t)((r0 + a_row) ^ 1) * PH;
    #pragma unroll
    for (int b0 = 0; b0 < 5; b0 += 3) {
      GR va[3], vh[3];
      #pragma unroll
      for (int j = 0; j < 3; ++j) {
        const int it = b0 + j;
        if (it >= 5) continue;
        const int kg = kg0 + (it << 3);
        if (kg < 38) {
          va[j].u = *(const uint4*)(ap + (kg << 3));
          vh[j].u = *(const uint4*)(hp + (kg << 3));
        }
      }
      #pragma unroll
      for (int j = 0; j < 3; ++j) {
        const int it = b0 + j;
        if (it >= 5) continue;
        const int kg = kg0 + (it << 3);
        if (kg >= 38) continue;
        GR o;
        #pragma unroll
        for (int q = 0; q < 8; ++q)
          o.s[q] = f2bf(bf2f(va[j].s[q]) - bf2f(vh[j].s[q]));
        *(uint4*)(S_lds + (size_t)((kg << 5) + a_row) * 8) = o.u;
      }
    }
  }
  __syncthreads();

  f32x4 acc[5][2];
  #pragma unroll
  for (int ni = 0; ni < 5; ++ni)
    #pragma unroll
    for (int i = 0; i < 2; ++i) acc[ni][i] = (f32x4)0.f;

  // ---- barrier-free k-loop ----
  #pragma unroll
  for (int kt = 0; kt < 10; ++kt) {
    int kg = kt * 4 + lg;
    if (kt * 4 + 3 >= 38) kg = (kg < 38) ? kg : 0;   // pad cols: W is zero there
    bf16x8 ef[2];
    #pragma unroll
    for (int i = 0; i < 2; ++i)
      ef[i] = *(const bf16x8*)(S_lds + (size_t)((kg * BR + i * 16 + lr)) * 8);
    const unsigned short* wk = wbt + (((size_t)kt * WGRAN + nt0 * 64 + l) << 3);
    #pragma unroll
    for (int ni = 0; ni < 5; ++ni) {
      if (ni < ntc) {
        const bf16x8 wf = *(const bf16x8*)(wk + ((size_t)ni << 9));
        #pragma unroll
        for (int i = 0; i < 2; ++i)
          acc[ni][i] = __builtin_amdgcn_mfma_f32_16x16x32_bf16(wf, ef[i], acc[ni][i], 0, 0, 0);
      }
    }
  }

  // ---- stage C tile (acc + bias, pre-relu) into LDS ----
  __syncthreads();
  #pragma unroll
  for (int ni = 0; ni < 5; ++ni) {
    if (ni >= ntc) continue;
    const int n = ((nt0 + ni) << 4) + (lg << 2);
    float4 bv = make_float4(0.f, 0.f, 0.f, 0.f);
    if (n < HID) bv = *(const float4*)(bias + n);
    #pragma unroll
    for (int i = 0; i < 2; ++i) {
      const int row = (i << 4) + lr;
      ushort4 o;
      o.x = f2bf(acc[ni][i][0] + bv.x);
      o.y = f2bf(acc[ni][i][1] + bv.y);
      o.z = f2bf(acc[ni][i][2] + bv.z);
      o.w = f2bf(acc[ni][i][3] + bv.w);
      *(ushort4*)(S_lds + row * CSTRIDE + n) = o;
    }
  }
  __syncthreads();

  // ---- linear write-out, 16B/lane: 32 rows x 38 uint4 granules ----
  {
    const size_t base = (size_t)r0 * PH;
    constexpr int WPIECE = BR * 38;               // 1216
    GR hz[5];
    int srow[5], sidx[5]; bool ok[5];
    #pragma unroll
    for (int j = 0; j < 5; ++j) {
      const int s = t + (j << 8);
      ok[j] = (s < WPIECE);
      if (ok[j]) {
        srow[j] = s / 38; sidx[j] = s - srow[j] * 38;
        hz[j].u = *(const uint4*)(h0 + base + (size_t)srow[j] * PH + (sidx[j] << 3));
      }
    }
    #pragma unroll
    for (int j = 0; j < 5; ++j) {
      if (!ok[j]) continue;
      GR c; c.u = *(const uint4*)(S_lds + srow[j] * CSTRIDE + (sidx[j] << 3));
      GR o;
      #pragma unroll
      for (int q = 0; q < 8; ++q)
        o.s[q] = f2bf(fmaxf(bf2f(c.s[q]) + bf2f(hz[j].s[q]), 0.f));
      *(uint4*)(outA + base + (size_t)srow[j] * PH + (sidx[j] << 3)) = o.u;
    }
  }
}

// ---------------- MFMA GEMM for MODE 0 (edge-init) / MODE 2 (node MLP) ------
template<int MODE, int KTILES>
__global__ __launch_bounds__(256, 5)
void gemm_kernel(const float* __restrict__ xin,
                 const int* __restrict__ rowidx,
                 const float* __restrict__ eaux,       // MODE0: edge_attr (f32)
                 const unsigned short* __restrict__ saux, // MODE2: s (bf16, PH)
                 const unsigned short* __restrict__ wbt,
                 const float* __restrict__ bias,
                 unsigned short* outA,
                 float* __restrict__ outF)
{
  constexpr int KEFF = (MODE == 0) ? (NF + EF) : (NF + HID);
  constexpr int NKG_A = (KEFF + 7) / 8;
  constexpr int STAGE_USH = NKG_A * BR * 8;
  constexpr int LDS_USH = (MODE == 2) ? STAGE_USH
                        : ((STAGE_USH > BR * CSTRIDE) ? STAGE_USH : BR * CSTRIDE);
  __shared__ unsigned short S_lds[LDS_USH];
  __shared__ int rowv[BR];

  const int t = threadIdx.x;
  const int l = t & 63;
  const int wave = t >> 6;
  const int lr = l & 15;
  const int lg = l >> 4;
  const int r0 = blockIdx.x * BR;
  const int nt0 = wave * 5;
  const int ntc = (wave == 3) ? 4 : 5;

  if (MODE == 0 && t < BR) rowv[t] = rowidx[r0 + t];
  __syncthreads();

  {
    constexpr int PIECES = STAGE_USH / 4;
    constexpr int SITER = (PIECES + 255) / 256;
    const int a_row = (t >> 1) & 31;
    const int a_c   = t >> 6;
    const int a_h4  = (t & 1) << 2;
    const int rv    = (MODE == 2) ? (r0 + a_row) : rowv[a_row];
    const float* xp = xin + (size_t)rv * NF;
    const float* ap = (MODE == 0) ? eaux + (size_t)(r0 + a_row) * EF - NF : nullptr;
    const unsigned short* sp = (MODE == 2) ? saux + (size_t)rv * PH : nullptr;
    const bool node_ok = (MODE != 2) || (rv < NN);
    #pragma unroll
    for (int b0 = 0; b0 < SITER; b0 += 4) {
      unsigned short uv[4][4];
      #pragma unroll
      for (int j = 0; j < 4; ++j) {
        const int it = b0 + j;
        if (it >= SITER) continue;
        const bool ok = (t + (it << 8)) < PIECES;
        const int k = ((a_c + 4 * it) << 3) + a_h4;
        #pragma unroll
        for (int q = 0; q < 4; ++q) {
          const int kk = k + q;
          unsigned short u = 0;
          if (ok && node_ok) {
            if (kk < NF) u = f2bf(xp[kk]);
            else if (kk < KEFF) u = (MODE == 0) ? f2bf(ap[kk]) : sp[kk - NF];
          }
          uv[j][q] = u;
        }
      }
      #pragma unroll
      for (int j = 0; j < 4; ++j) {
        const int it = b0 + j;
        if (it >= SITER) continue;
        if ((t + (it << 8)) >= PIECES) continue;
        ushort4 o;
        o.x = uv[j][0]; o.y = uv[j][1]; o.z = uv[j][2]; o.w = uv[j][3];
        *(ushort4*)(S_lds + (size_t)(t + (it << 8)) * 4) = o;
      }
    }
  }
  __syncthreads();

  f32x4 acc[5][2];
  #pragma unroll
  for (int ni = 0; ni < 5; ++ni)
    #pragma unroll
    for (int i = 0; i < 2; ++i) acc[ni][i] = (f32x4)0.f;

  constexpr int NKG = (KEFF + 7) / 8;
  #pragma unroll
  for (int kt = 0; kt < KTILES; ++kt) {
    int kg = kt * 4 + lg;
    if (kt * 4 + 3 >= NKG) kg = (kg < NKG) ? kg : 0;
    bf16x8 ef[2];
    #pragma unroll
    for (int i = 0; i < 2; ++i)
      ef[i] = *(const bf16x8*)(S_lds + (size_t)((kg * BR + i * 16 + lr)) * 8);
    const unsigned short* wk = wbt + (((size_t)kt * WGRAN + nt0 * 64 + l) << 3);
    #pragma unroll
    for (int ni = 0; ni < 5; ++ni) {
      if (ni < ntc) {
        const bf16x8 wf = *(const bf16x8*)(wk + ((size_t)ni << 9));
        #pragma unroll
        for (int i = 0; i < 2; ++i)
          acc[ni][i] = __builtin_amdgcn_mfma_f32_16x16x32_bf16(wf, ef[i], acc[ni][i], 0, 0, 0);
      }
    }
  }

  if (MODE == 2) {
    #pragma unroll
    for (int ni = 0; ni < 5; ++ni) {
      if (ni >= ntc) continue;
      const int n = ((nt0 + ni) << 4) + (lg << 2);
      if (n >= HID) continue;
      const float4 bv = *(const float4*)(bias + n);
      #pragma unroll
      for (int i = 0; i < 2; ++i) {
        const int node = r0 + (i << 4) + lr;
        if (node >= NN) continue;
        float v0 = fmaxf(acc[ni][i][0] + bv.x, 0.f);
        float v1 = fmaxf(acc[ni][i][1] + bv.y, 0.f);
        float v2 = fmaxf(acc[ni][i][2] + bv.z, 0.f);
        float v3 = fmaxf(acc[ni][i][3] + bv.w, 0.f);
        *(float4*)(outF + (size_t)node * HID + n) = make_float4(v0, v1, v2, v3);
      }
    }
    return;
  }

  // ---- MODE 0 epilogue: bias+relu, C-tile, 16B/lane write ----
  __syncthreads();
  #pragma unroll
  for (int ni = 0; ni < 5; ++ni) {
    if (ni >= ntc) continue;
    const int n = ((nt0 + ni) << 4) + (lg << 2);
    float4 bv = make_float4(0.f, 0.f, 0.f, 0.f);
    if (n < HID) bv = *(const float4*)(bias + n);
    #pragma unroll
    for (int i = 0; i < 2; ++i) {
      const int row = (i << 4) + lr;
      ushort4 o;
      o.x = f2bf(fmaxf(acc[ni][i][0] + bv.x, 0.f));
      o.y = f2bf(fmaxf(acc[ni][i][1] + bv.y, 0.f));
      o.z = f2bf(fmaxf(acc[ni][i][2] + bv.z, 0.f));
      o.w = f2bf(fmaxf(acc[ni][i][3] + bv.w, 0.f));
      *(ushort4*)(S_lds + row * CSTRIDE + n) = o;
    }
  }
  __syncthreads();
  {
    const size_t base = (size_t)r0 * PH;
    constexpr int WPIECE = BR * 38;               // 1216
    #pragma unroll
    for (int j = 0; j < 5; ++j) {
      const int s = t + (j << 8);
      if (s >= WPIECE) continue;
      const int row = s / 38;
      const int idx = s - row * 38;
      const uint4 c = *(const uint4*)(S_lds + row * CSTRIDE + (idx << 3));
      *(uint4*)(outA + base + (size_t)row * PH + (idx << 3)) = c;
    }
  }
}

// ---------------- output init + fused dot/pool ----------------
__global__ void init_out_kernel(float* __restrict__ out, const float* __restrict__ b_ffn) {
  int t = threadIdx.x;
  if (t < NG) out[t] = b_ffn[0];
}

__global__ void dotpool_kernel(const float* __restrict__ hn, const float* __restrict__ wffn,
                               const int* __restrict__ batch, float* __restrict__ out) {
  const int wave = threadIdx.x >> 6, lane = threadIdx.x & 63;
  const int v = blockIdx.x * 4 + wave;
  if (v >= NN) return;
  float s = 0.f;
  for (int j = lane; j < HID; j += 64) s += hn[(size_t)v * HID + j] * wffn[j];
  #pragma unroll
  for (int off = 32; off > 0; off >>= 1) s += __shfl_down(s, off, 64);
  if (lane == 0) atomicAdd(&out[batch[v]], s);
}

// ---------------- launch ----------------
extern "C" void kernel_launch(void* const* d_in, const int* in_sizes, int n_in,
                              void* d_out, int out_size, void* d_ws, size_t ws_size,
                              hipStream_t stream) {
  const float* x     = (const float*)d_in[0];
  const int*   eidx  = (const int*)d_in[1];
  const float* eattr = (const float*)d_in[2];
  const int*   batch = (const int*)d_in[3];
  const float* W_ei  = (const float*)d_in[4];
  const float* b_ei  = (const float*)d_in[5];
  const float* Ws    = (const float*)d_in[6];
  const float* bs    = (const float*)d_in[7];
  const float* W_en  = (const float*)d_in[8];
  const float* b_en  = (const float*)d_in[9];
  const float* W_ffn = (const float*)d_in[10];
  const float* b_ffn = (const float*)d_in[11];
  float* out = (float*)d_out;

  const int* row  = eidx;
  const int* colv = eidx + NE;

  // workspace layout (~215 MB), PH=304-stride rows 16B-aligned
  char* ws = (char*)d_ws;
  unsigned short* h0  = (unsigned short*)(ws + 0);              //  97,280,000 B
  unsigned short* h   = (unsigned short*)(ws + 97280000ull);    //  97,280,000 B
  unsigned short* abf = (unsigned short*)(ws + 194560000ull);   //   6,080,000 B (bf16)
  float* hn           = (float*)(ws + 200640000ull);            //  12,000,000 B (stride 300)
  int* indptr         = (int*)(ws + 212640000ull);              //      40,004 B
  int* cnt            = (int*)(ws + 212680192ull);              //      40,000 B
  int* eids           = (int*)(ws + 212720384ull);              //     640,000 B
  unsigned short* wbt0 = (unsigned short*)(ws + 213360384ull);  //      97,280 B
  unsigned short* wbtC = (unsigned short*)(ws + 213457664ull);  //     583,680 B (3 layers)
  unsigned short* wbtN = (unsigned short*)(ws + 214041344ull);  //     272,384 B

  // CSR over col (scatter restores cnt to 0)
  zero_kernel<<<(NN + 255) / 256, 256, 0, stream>>>(cnt, NN);
  hist_kernel<<<NE / 256, 256, 0, stream>>>(colv, cnt);
  scan_kernel<<<1, 1024, 0, stream>>>(cnt, indptr);
  scatter_kernel<<<NE / 256, 256, 0, stream>>>(colv, indptr, cnt, eids);

  // weight pre-transposes (bf16, MFMA fragment order, zero-padded tails)
  wtrans_kernel<<<5 * NT, 64, 0, stream>>>(W_ei, NF + EF, wbt0);
  for (int lyr = 0; lyr < 3; ++lyr)
    wtrans_kernel<<<10 * NT, 64, 0, stream>>>(Ws + (size_t)lyr * HID * HID, HID,
                                              wbtC + (size_t)lyr * 10 * WGRAN * 8);
  wtrans_kernel<<<14 * NT, 64, 0, stream>>>(W_en, NF + HID, wbtN);

  // h0 = relu([x[row]|ea] @ W_ei + b_ei)
  gemm_kernel<0, 5><<<NE / BR, 256, 0, stream>>>(
      x, row, eattr, nullptr, wbt0, b_ei, h0, nullptr);

  // layer 0: a = segsum(h0); h = relu((a[row]-h0^1)@W0 + b0 + h0)
  segsum_kernel<<<NN, 256, 0, stream>>>(h0, indptr, eids, abf);
  conv_kernel<<<NE / BR, 256, 0, stream>>>(row, abf, h0, h0, wbtC, bs, h);

  // layers 1,2: in-place on h
  for (int lyr = 1; lyr < 3; ++lyr) {
    segsum_kernel<<<NN, 256, 0, stream>>>(h, indptr, eids, abf);
    conv_kernel<<<NE / BR, 256, 0, stream>>>(
        row, abf, h, h0,
        wbtC + (size_t)lyr * 10 * WGRAN * 8,
        bs + (size_t)lyr * HID, h);
  }

  // s = segsum(h, col); hn = relu([x|s] @ W_en + b_en)
  segsum_kernel<<<NN, 256, 0, stream>>>(h, indptr, eids, abf);
  gemm_kernel<2, 14><<<(NN + BR - 1) / BR, 256, 0, stream>>>(
      x, nullptr, nullptr, abf, wbtN, b_en, nullptr, hn);

  // out[g] = b_ffn + sum_{batch[v]=g} hn[v] . W_ffn
  init_out_kernel<<<1, 64, 0, stream>>>(out, b_ffn);
  dotpool_kernel<<<NN / 4, 256, 0, stream>>>(hn, W_ffn, batch, out);
}